// Round 2
// baseline (61.802 us; speedup 1.0000x reference)
//
#include <hip/hip_runtime.h>
#include <math.h>

#define NR 256   // rules
#define NF 128   // features
#define TB 8     // batch rows per main-kernel block

// ---------------------------------------------------------------------------
// prep: per (rule, feature) expand -(d-mu)^2/(2 sigma^2) = a*d^2 + b*d + (c)
//   a = -1/(2 s^2), b = 2 mu/(2 s^2), Cr[r] = sum_f -mu^2/(2 s^2)
// also repack w3 into aligned W[r][f] = w3[r][1+f], W0[r] = w3[r][0].
// ---------------------------------------------------------------------------
__global__ __launch_bounds__(128) void prep_kernel(
    const float* __restrict__ mu, const float* __restrict__ sigma,
    const float* __restrict__ w3,
    float* __restrict__ A, float* __restrict__ B, float* __restrict__ W,
    float* __restrict__ Cr, float* __restrict__ W0)
{
    const int r = blockIdx.x;
    const int f = threadIdx.x;
    const size_t i = (size_t)r * NF + f;
    const float s = sigma[i];
    const float m = mu[i];
    const float c = 0.5f / fmaxf(s * s, 1e-30f);  // clamp: avoid inf -> NaN
    const float a = -c;
    const float b = 2.0f * c * m;
    float cc = -c * m * m;
    A[i] = a;
    B[i] = b;
    W[i] = w3[(size_t)r * (NF + 1) + 1 + f];
    #pragma unroll
    for (int off = 32; off > 0; off >>= 1) cc += __shfl_down(cc, off);
    __shared__ float tmp[2];
    if ((f & 63) == 0) tmp[f >> 6] = cc;
    __syncthreads();
    if (f == 0) {
        Cr[r] = tmp[0] + tmp[1];
        W0[r] = w3[(size_t)r * (NF + 1)];
    }
}

// ---------------------------------------------------------------------------
// main: thread = rule (256 threads), TB batch rows per block.
//   S[b] = Cr + sum_f (a*d + b)*d ;  conq = W0 + sum_f d*W
//   rule = exp(S) - 28 ; out = sigmoid(sum_r rule*conq / sum_r rule)
// ---------------------------------------------------------------------------
__global__ __launch_bounds__(256) void fnn_main(
    const float* __restrict__ data,
    const float* __restrict__ A, const float* __restrict__ B,
    const float* __restrict__ W, const float* __restrict__ Cr,
    const float* __restrict__ W0,
    float* __restrict__ out)
{
    __shared__ float d_tile[TB][NF];   // 4 KB
    __shared__ float red[TB][2][4];

    const int tid = threadIdx.x;
    const int b0  = blockIdx.x * TB;

    // stage TB*NF = 1024 floats = 256 float4, one per thread, coalesced
    {
        const float4* src = (const float4*)(data + (size_t)b0 * NF);
        ((float4*)(&d_tile[0][0]))[tid] = src[tid];
    }
    __syncthreads();

    const float* A_r = A + (size_t)tid * NF;
    const float* B_r = B + (size_t)tid * NF;
    const float* W_r = W + (size_t)tid * NF;

    float S[TB], Q[TB];
    #pragma unroll
    for (int b = 0; b < TB; ++b) { S[b] = 0.f; Q[b] = 0.f; }

    #pragma unroll 2
    for (int f = 0; f < NF; f += 4) {
        const float4 a4 = *(const float4*)(A_r + f);
        const float4 b4 = *(const float4*)(B_r + f);
        const float4 w4 = *(const float4*)(W_r + f);
        #pragma unroll
        for (int b = 0; b < TB; ++b) {
            const float4 d4 = *(const float4*)(&d_tile[b][f]);  // wave-uniform -> broadcast
            float t;
            t = fmaf(a4.x, d4.x, b4.x); S[b] = fmaf(d4.x, t, S[b]); Q[b] = fmaf(d4.x, w4.x, Q[b]);
            t = fmaf(a4.y, d4.y, b4.y); S[b] = fmaf(d4.y, t, S[b]); Q[b] = fmaf(d4.y, w4.y, Q[b]);
            t = fmaf(a4.z, d4.z, b4.z); S[b] = fmaf(d4.z, t, S[b]); Q[b] = fmaf(d4.z, w4.z, Q[b]);
            t = fmaf(a4.w, d4.w, b4.w); S[b] = fmaf(d4.w, t, S[b]); Q[b] = fmaf(d4.w, w4.w, Q[b]);
        }
    }

    const float base = Cr[tid];
    const float bias = W0[tid];

    #pragma unroll
    for (int b = 0; b < TB; ++b) {
        float rule = __expf(S[b] + base) - 28.0f;   // RULE_OFFSET (10 ^ -18 == -28)
        float rc   = rule * (bias + Q[b]);
        #pragma unroll
        for (int off = 32; off > 0; off >>= 1) {
            rule += __shfl_down(rule, off);
            rc   += __shfl_down(rc,   off);
        }
        if ((tid & 63) == 0) {
            red[b][0][tid >> 6] = rule;
            red[b][1][tid >> 6] = rc;
        }
    }
    __syncthreads();

    if (tid < TB) {
        const float den = red[tid][0][0] + red[tid][0][1] + red[tid][0][2] + red[tid][0][3];
        const float num = red[tid][1][0] + red[tid][1][1] + red[tid][1][2] + red[tid][1][3];
        out[b0 + tid] = 1.0f / (1.0f + __expf(-(num / den)));
    }
}

// ---------------------------------------------------------------------------
// fallback (ws too small): fused version, computes a/b from sigma/mu inline.
// ---------------------------------------------------------------------------
__global__ __launch_bounds__(256) void fnn_fused(
    const float* __restrict__ data,
    const float* __restrict__ mu, const float* __restrict__ sigma,
    const float* __restrict__ w3,
    float* __restrict__ out)
{
    __shared__ float d_tile[TB][NF];
    __shared__ float red[TB][2][4];

    const int tid = threadIdx.x;
    const int b0  = blockIdx.x * TB;
    {
        const float4* src = (const float4*)(data + (size_t)b0 * NF);
        ((float4*)(&d_tile[0][0]))[tid] = src[tid];
    }
    __syncthreads();

    const float* mu_r = mu    + (size_t)tid * NF;
    const float* sg_r = sigma + (size_t)tid * NF;
    const float* w_r  = w3    + (size_t)tid * (NF + 1);

    float S[TB], Q[TB];
    #pragma unroll
    for (int b = 0; b < TB; ++b) { S[b] = 0.f; Q[b] = 0.f; }

    #pragma unroll 2
    for (int f = 0; f < NF; f += 4) {
        const float4 m4 = *(const float4*)(mu_r + f);
        const float4 s4 = *(const float4*)(sg_r + f);
        const float w0 = w_r[1 + f + 0], w1 = w_r[1 + f + 1];
        const float w2 = w_r[1 + f + 2], w3v = w_r[1 + f + 3];
        float4 c4;
        c4.x = -0.5f / fmaxf(s4.x * s4.x, 1e-30f);
        c4.y = -0.5f / fmaxf(s4.y * s4.y, 1e-30f);
        c4.z = -0.5f / fmaxf(s4.z * s4.z, 1e-30f);
        c4.w = -0.5f / fmaxf(s4.w * s4.w, 1e-30f);
        #pragma unroll
        for (int b = 0; b < TB; ++b) {
            const float4 d4 = *(const float4*)(&d_tile[b][f]);
            float t;
            t = d4.x - m4.x; S[b] = fmaf(t * t, c4.x, S[b]); Q[b] = fmaf(d4.x, w0,  Q[b]);
            t = d4.y - m4.y; S[b] = fmaf(t * t, c4.y, S[b]); Q[b] = fmaf(d4.y, w1,  Q[b]);
            t = d4.z - m4.z; S[b] = fmaf(t * t, c4.z, S[b]); Q[b] = fmaf(d4.z, w2,  Q[b]);
            t = d4.w - m4.w; S[b] = fmaf(t * t, c4.w, S[b]); Q[b] = fmaf(d4.w, w3v, Q[b]);
        }
    }

    const float bias = w_r[0];
    #pragma unroll
    for (int b = 0; b < TB; ++b) {
        float rule = __expf(S[b]) - 28.0f;
        float rc   = rule * (bias + Q[b]);
        #pragma unroll
        for (int off = 32; off > 0; off >>= 1) {
            rule += __shfl_down(rule, off);
            rc   += __shfl_down(rc,   off);
        }
        if ((tid & 63) == 0) {
            red[b][0][tid >> 6] = rule;
            red[b][1][tid >> 6] = rc;
        }
    }
    __syncthreads();
    if (tid < TB) {
        const float den = red[tid][0][0] + red[tid][0][1] + red[tid][0][2] + red[tid][0][3];
        const float num = red[tid][1][0] + red[tid][1][1] + red[tid][1][2] + red[tid][1][3];
        out[b0 + tid] = 1.0f / (1.0f + __expf(-(num / den)));
    }
}

extern "C" void kernel_launch(void* const* d_in, const int* in_sizes, int n_in,
                              void* d_out, int out_size, void* d_ws, size_t ws_size,
                              hipStream_t stream) {
    const float* data  = (const float*)d_in[0];
    const float* mu    = (const float*)d_in[1];
    const float* sigma = (const float*)d_in[2];
    const float* w3    = (const float*)d_in[3];
    float* out = (float*)d_out;

    const int batch = in_sizes[0] / NF;   // 8192
    const size_t need = (size_t)(3 * NR * NF + 2 * NR) * sizeof(float);  // ~396 KB

    if (ws_size >= need) {
        float* A  = (float*)d_ws;
        float* B  = A + NR * NF;
        float* W  = B + NR * NF;
        float* Cr = W + NR * NF;
        float* W0 = Cr + NR;
        prep_kernel<<<NR, NF, 0, stream>>>(mu, sigma, w3, A, B, W, Cr, W0);
        fnn_main<<<batch / TB, 256, 0, stream>>>(data, A, B, W, Cr, W0, out);
    } else {
        fnn_fused<<<batch / TB, 256, 0, stream>>>(data, mu, sigma, w3, out);
    }
}

// Round 3
// 41.179 us; speedup vs baseline: 1.5008x; 1.5008x over previous
//
#include <hip/hip_runtime.h>
#include <math.h>

#define NR 256   // rules
#define NF 128   // features
#define TB 16    // batch rows per main-kernel block

// ---------------------------------------------------------------------------
// prep: per (rule, feature) expand -(d-mu)^2/(2 s^2) = a*d^2 + b*d + c
//   a = -1/(2 s^2), b = 2 mu/(2 s^2), Cr[r] = sum_f -mu^2/(2 s^2)
// Writes TRANSPOSED (feature-major) so the main kernel's param reads are
// coalesced across lanes (lane = rule):
//   PT2[f][r] = {a, b}   (float2)
//   WT [f][r] = w3[r][1+f]
// Block = rule (coalesced reads of mu/sigma/w3 rows), 128 threads = feature.
// ---------------------------------------------------------------------------
__global__ __launch_bounds__(128) void prep_kernel(
    const float* __restrict__ mu, const float* __restrict__ sigma,
    const float* __restrict__ w3,
    float2* __restrict__ PT2, float* __restrict__ WT,
    float* __restrict__ Cr, float* __restrict__ W0)
{
    const int r = blockIdx.x;
    const int f = threadIdx.x;
    const size_t i = (size_t)r * NF + f;
    const float s = sigma[i];
    const float m = mu[i];
    const float c = 0.5f / fmaxf(s * s, 1e-30f);  // clamp: avoid inf -> NaN
    const float a = -c;
    const float b = 2.0f * c * m;

    PT2[(size_t)f * NR + r] = make_float2(a, b);
    WT [(size_t)f * NR + r] = w3[(size_t)r * (NF + 1) + 1 + f];

    float cc = -c * m * m;
    #pragma unroll
    for (int off = 32; off > 0; off >>= 1) cc += __shfl_down(cc, off);
    __shared__ float tmp[2];
    if ((f & 63) == 0) tmp[f >> 6] = cc;
    __syncthreads();
    if (f == 0) {
        Cr[r] = tmp[0] + tmp[1];
        W0[r] = w3[(size_t)r * (NF + 1)];
    }
}

// ---------------------------------------------------------------------------
// main: thread = rule (256 threads), TB batch rows per block.
//   S[b] = Cr + sum_f (a*d + b)*d ;  conq = W0 + sum_f d*W
//   rule = exp(S) - 28 ; out = sigmoid(sum_r rule*conq / sum_r rule)
// Param reads now coalesced: lane r reads PT2[f*NR + r] / WT[f*NR + r].
// ---------------------------------------------------------------------------
__global__ __launch_bounds__(256) void fnn_main(
    const float* __restrict__ data,
    const float2* __restrict__ PT2, const float* __restrict__ WT,
    const float* __restrict__ Cr, const float* __restrict__ W0,
    float* __restrict__ out)
{
    __shared__ float d_tile[TB][NF];   // 8 KB
    __shared__ float red[TB][2][4];

    const int tid = threadIdx.x;       // == rule id
    const int b0  = blockIdx.x * TB;

    // stage TB*NF = 2048 floats = 512 float4; 256 threads -> 2 each, coalesced
    {
        const float4* src = (const float4*)(data + (size_t)b0 * NF);
        float4* dst = (float4*)(&d_tile[0][0]);
        dst[tid]       = src[tid];
        dst[tid + 256] = src[tid + 256];
    }
    __syncthreads();

    float S[TB], Q[TB];
    #pragma unroll
    for (int b = 0; b < TB; ++b) { S[b] = 0.f; Q[b] = 0.f; }

    #pragma unroll 2
    for (int f = 0; f < NF; f += 4) {
        // coalesced param loads: lane r -> consecutive addresses
        const float2 ab0 = PT2[(size_t)(f + 0) * NR + tid];
        const float2 ab1 = PT2[(size_t)(f + 1) * NR + tid];
        const float2 ab2 = PT2[(size_t)(f + 2) * NR + tid];
        const float2 ab3 = PT2[(size_t)(f + 3) * NR + tid];
        const float w0 = WT[(size_t)(f + 0) * NR + tid];
        const float w1 = WT[(size_t)(f + 1) * NR + tid];
        const float w2 = WT[(size_t)(f + 2) * NR + tid];
        const float w3v = WT[(size_t)(f + 3) * NR + tid];

        #pragma unroll
        for (int b = 0; b < TB; ++b) {
            const float4 d4 = *(const float4*)(&d_tile[b][f]);  // wave-uniform -> LDS broadcast
            float t;
            t = fmaf(ab0.x, d4.x, ab0.y); S[b] = fmaf(d4.x, t, S[b]); Q[b] = fmaf(d4.x, w0,  Q[b]);
            t = fmaf(ab1.x, d4.y, ab1.y); S[b] = fmaf(d4.y, t, S[b]); Q[b] = fmaf(d4.y, w1,  Q[b]);
            t = fmaf(ab2.x, d4.z, ab2.y); S[b] = fmaf(d4.z, t, S[b]); Q[b] = fmaf(d4.z, w2,  Q[b]);
            t = fmaf(ab3.x, d4.w, ab3.y); S[b] = fmaf(d4.w, t, S[b]); Q[b] = fmaf(d4.w, w3v, Q[b]);
        }
    }

    const float base = Cr[tid];
    const float bias = W0[tid];

    #pragma unroll
    for (int b = 0; b < TB; ++b) {
        float rule = __expf(S[b] + base) - 28.0f;   // RULE_OFFSET (10 ^ -18 == -28)
        float rc   = rule * (bias + Q[b]);
        #pragma unroll
        for (int off = 32; off > 0; off >>= 1) {
            rule += __shfl_down(rule, off);
            rc   += __shfl_down(rc,   off);
        }
        if ((tid & 63) == 0) {
            red[b][0][tid >> 6] = rule;
            red[b][1][tid >> 6] = rc;
        }
    }
    __syncthreads();

    if (tid < TB) {
        const float den = red[tid][0][0] + red[tid][0][1] + red[tid][0][2] + red[tid][0][3];
        const float num = red[tid][1][0] + red[tid][1][1] + red[tid][1][2] + red[tid][1][3];
        out[b0 + tid] = 1.0f / (1.0f + __expf(-(num / den)));
    }
}

// ---------------------------------------------------------------------------
// fallback (ws too small): fused version (round-2 structure, TB=8).
// ---------------------------------------------------------------------------
#define TBF 8
__global__ __launch_bounds__(256) void fnn_fused(
    const float* __restrict__ data,
    const float* __restrict__ mu, const float* __restrict__ sigma,
    const float* __restrict__ w3,
    float* __restrict__ out)
{
    __shared__ float d_tile[TBF][NF];
    __shared__ float red[TBF][2][4];

    const int tid = threadIdx.x;
    const int b0  = blockIdx.x * TBF;
    {
        const float4* src = (const float4*)(data + (size_t)b0 * NF);
        ((float4*)(&d_tile[0][0]))[tid] = src[tid];
    }
    __syncthreads();

    const float* mu_r = mu    + (size_t)tid * NF;
    const float* sg_r = sigma + (size_t)tid * NF;
    const float* w_r  = w3    + (size_t)tid * (NF + 1);

    float S[TBF], Q[TBF];
    #pragma unroll
    for (int b = 0; b < TBF; ++b) { S[b] = 0.f; Q[b] = 0.f; }

    #pragma unroll 2
    for (int f = 0; f < NF; f += 4) {
        const float4 m4 = *(const float4*)(mu_r + f);
        const float4 s4 = *(const float4*)(sg_r + f);
        const float w0 = w_r[1 + f + 0], w1 = w_r[1 + f + 1];
        const float w2 = w_r[1 + f + 2], w3v = w_r[1 + f + 3];
        float4 c4;
        c4.x = -0.5f / fmaxf(s4.x * s4.x, 1e-30f);
        c4.y = -0.5f / fmaxf(s4.y * s4.y, 1e-30f);
        c4.z = -0.5f / fmaxf(s4.z * s4.z, 1e-30f);
        c4.w = -0.5f / fmaxf(s4.w * s4.w, 1e-30f);
        #pragma unroll
        for (int b = 0; b < TBF; ++b) {
            const float4 d4 = *(const float4*)(&d_tile[b][f]);
            float t;
            t = d4.x - m4.x; S[b] = fmaf(t * t, c4.x, S[b]); Q[b] = fmaf(d4.x, w0,  Q[b]);
            t = d4.y - m4.y; S[b] = fmaf(t * t, c4.y, S[b]); Q[b] = fmaf(d4.y, w1,  Q[b]);
            t = d4.z - m4.z; S[b] = fmaf(t * t, c4.z, S[b]); Q[b] = fmaf(d4.z, w2,  Q[b]);
            t = d4.w - m4.w; S[b] = fmaf(t * t, c4.w, S[b]); Q[b] = fmaf(d4.w, w3v, Q[b]);
        }
    }

    const float bias = w_r[0];
    #pragma unroll
    for (int b = 0; b < TBF; ++b) {
        float rule = __expf(S[b]) - 28.0f;
        float rc   = rule * (bias + Q[b]);
        #pragma unroll
        for (int off = 32; off > 0; off >>= 1) {
            rule += __shfl_down(rule, off);
            rc   += __shfl_down(rc,   off);
        }
        if ((tid & 63) == 0) {
            red[b][0][tid >> 6] = rule;
            red[b][1][tid >> 6] = rc;
        }
    }
    __syncthreads();
    if (tid < TBF) {
        const float den = red[tid][0][0] + red[tid][0][1] + red[tid][0][2] + red[tid][0][3];
        const float num = red[tid][1][0] + red[tid][1][1] + red[tid][1][2] + red[tid][1][3];
        out[b0 + tid] = 1.0f / (1.0f + __expf(-(num / den)));
    }
}

extern "C" void kernel_launch(void* const* d_in, const int* in_sizes, int n_in,
                              void* d_out, int out_size, void* d_ws, size_t ws_size,
                              hipStream_t stream) {
    const float* data  = (const float*)d_in[0];
    const float* mu    = (const float*)d_in[1];
    const float* sigma = (const float*)d_in[2];
    const float* w3    = (const float*)d_in[3];
    float* out = (float*)d_out;

    const int batch = in_sizes[0] / NF;   // 8192
    // PT2 (2*NR*NF) + WT (NR*NF) + Cr (NR) + W0 (NR) floats == 395,264 B
    const size_t need = (size_t)(3 * NR * NF + 2 * NR) * sizeof(float);

    if (ws_size >= need) {
        float2* PT2 = (float2*)d_ws;
        float*  WT  = (float*)(PT2 + (size_t)NR * NF);
        float*  Cr  = WT + (size_t)NR * NF;
        float*  W0  = Cr + NR;
        prep_kernel<<<NR, NF, 0, stream>>>(mu, sigma, w3, PT2, WT, Cr, W0);
        fnn_main<<<batch / TB, 256, 0, stream>>>(data, PT2, WT, Cr, W0, out);
    } else {
        fnn_fused<<<batch / TBF, 256, 0, stream>>>(data, mu, sigma, w3, out);
    }
}